// Round 7
// baseline (538.141 us; speedup 1.0000x reference)
//
#include <hip/hip_runtime.h>
#include <stdint.h>

typedef unsigned short u16;
typedef __bf16 bf16x8 __attribute__((ext_vector_type(8)));
typedef float floatx4 __attribute__((ext_vector_type(4)));

// ---------------- fused global amax (x and W in one launch) ----------------
__global__ void amax_both_k(const float4* __restrict__ x, long nx4,
                            const float4* __restrict__ w, long nw4,
                            unsigned* slots, int gx) {
    const float4* src; long n4; int bid, nb; unsigned* slot;
    if ((int)blockIdx.x < gx) { src = x; n4 = nx4; bid = blockIdx.x; nb = gx; slot = slots; }
    else { src = w; n4 = nw4; bid = blockIdx.x - gx; nb = gridDim.x - gx; slot = slots + 1; }
    float m = 0.0f;
    long stride = (long)nb * blockDim.x;
    for (long i = (long)bid * blockDim.x + threadIdx.x; i < n4; i += stride) {
        float4 v = src[i];
        m = fmaxf(m, fmaxf(fmaxf(fabsf(v.x), fabsf(v.y)), fmaxf(fabsf(v.z), fabsf(v.w))));
    }
    #pragma unroll
    for (int off = 32; off > 0; off >>= 1)
        m = fmaxf(m, __shfl_down(m, off, 64));
    __shared__ float sm[4];
    int lane = threadIdx.x & 63, wv = threadIdx.x >> 6;
    if (lane == 0) sm[wv] = m;
    __syncthreads();
    if (threadIdx.x == 0) {
        m = fmaxf(fmaxf(sm[0], sm[1]), fmaxf(sm[2], sm[3]));
        atomicMax(slot, __float_as_uint(m));   // nonneg fp32: uint order == float order
    }
}

// ---------------- quantization helpers ----------------
// RNE float -> e4m3fn for v in [0, 448]
__device__ __forceinline__ float e4m3_rne(float v) {
    unsigned u = __float_as_uint(v);
    u += 0x7FFFFu + ((u >> 20) & 1u);            // RNE keep 3 mantissa bits
    float hi = __uint_as_float(u & 0xFFF00000u);
    float lo = rintf(v * 512.0f) * 0.001953125f; // subnormal, step 2^-9
    return (v < 0.015625f) ? lo : hi;
}

// RNE to fp4 e2m1 {0,±0.5,1,1.5,2,3,4,6}
__device__ __forceinline__ float fp4_rne(float x) {
    float a = fminf(fabsf(x), 6.0f);
    unsigned u = __float_as_uint(a);
    u += 0x1FFFFFu + ((u >> 22) & 1u);           // RNE keep 1 mantissa bit (a >= 1)
    float hi = __uint_as_float(u & 0xFFC00000u);
    float lo = rintf(a + a) * 0.5f;              // a < 1: fixed step 0.5
    float q = (a < 1.0f) ? lo : hi;
    return copysignf(q, x);
}

// pack two fp32 (exactly representable in bf16) into 2 bf16 bit patterns
__device__ __forceinline__ unsigned pack2(float d0, float d1) {
    return (__float_as_uint(d0) >> 16) | (__float_as_uint(d1) & 0xFFFF0000u);
}

// R6: COALESCED quant. One float4 per lane (16B/lane coalesced); the 16-elem nvfp4
// block spans the aligned lane-quad [4j..4j+3]; block amax via __shfl_xor width-4.
// Same fp32 op sequence as reference (am -> sf -> r -> fp4*sf) => identical results.
// nx4 % 64 == 0 so waves (and quads) never straddle the x/W boundary.
__global__ void quant_both_k(const float4* __restrict__ x4, const float4* __restrict__ w4,
                             uint2* __restrict__ Aq2, uint2* __restrict__ Bq2,
                             const unsigned* __restrict__ slots, long nx4, long ntot4) {
    float ag0 = __uint_as_float(slots[0]);
    float ag1 = __uint_as_float(slots[1]);
    float gs0 = 2688.0f / ag0, gs1 = 2688.0f / ag1;
    float t0 = gs0 / 6.0f,     t1 = gs1 / 6.0f;
    long stride = (long)gridDim.x * blockDim.x;
    for (long i = (long)blockIdx.x * blockDim.x + threadIdx.x; i < ntot4; i += stride) {
        bool isx = i < nx4;
        float4 v = isx ? x4[i] : w4[i - nx4];
        float gs = isx ? gs0 : gs1;
        float t  = isx ? t0  : t1;
        float am = fmaxf(fmaxf(fabsf(v.x), fabsf(v.y)), fmaxf(fabsf(v.z), fabsf(v.w)));
        am = fmaxf(am, __shfl_xor(am, 1, 4));
        am = fmaxf(am, __shfl_xor(am, 2, 4));
        float sf = e4m3_rne(am * t);
        float r = gs / (sf > 0.0f ? sf : 1.0f);
        uint2 o;
        o.x = pack2(fp4_rne(v.x * r) * sf, fp4_rne(v.y * r) * sf);
        o.y = pack2(fp4_rne(v.z * r) * sf, fp4_rne(v.w * r) * sf);
        if (isx) Aq2[i] = o; else Bq2[i - nx4] = o;
    }
}

// ---------------- GEMM: 256x256 tile, BK=64, 4-phase schedule with ----------------
// register-double-buffered fragment prefetch (R6; R7 = same design, offset passed
// as "i"-constraint %c immediate instead of stringified expression — de-risk).
// 8 waves (2M x 4N), per-wave 128x64, 16x16x32 bf16 MFMA. LDS 128 KB (2dbuf A,B).
// Frag sets: af_a/af_b (8 frags each), bf_a/bf_b (4 each). Reads for quadrant q are
// issued ONE PHASE EARLY; consuming phase waits counted lgkmcnt(#reads just issued):
//   ph1: q(0,0) af_a,bf_a | issue bf_b(4)        | stage A(s+1)h1 | lgkmcnt(4)
//   ph2: q(0,1) af_a,bf_b | issue af_b(8)        |                | lgkmcnt(8)
//   ph3: q(1,0) af_b,bf_a |                      | stage B(s+2)h0 | lgkmcnt(0); vmcnt(2) pre-barrier
//   ph4: q(1,1) af_b,bf_b | issue af_a',bf_a'(12)| stage B(s+2)h1 + A(s+2)h0 | no wait
// vmcnt(2) at ph3-end (before its trailing barrier) retires A(s+1),B(s+1) in every
// wave => ph4's next-tile reads are cross-wave safe. All LDS overwrites are
// barrier-ordered after their readers' lgkm-retire (no latency assumptions).
#define KTILE 64

#define SFENCE() __builtin_amdgcn_sched_barrier(0)
#define BAR() do { asm volatile("" ::: "memory"); SFENCE(); \
    __builtin_amdgcn_s_barrier(); SFENCE(); asm volatile("" ::: "memory"); } while (0)

// ds_read_b128 with compile-time byte offset immediate (%c prints bare integer)
#define DSR128O(D, VB, IMM) asm volatile("ds_read_b128 %0, %1 offset:%c2" \
    : "=v"(D) : "v"(VB), "i"(IMM))

#define STAGE_SLOT(GS, LS) do { \
    __builtin_amdgcn_global_load_lds((const __attribute__((address_space(1))) void*)(GS), \
        (__attribute__((address_space(3))) void*)(LS), 16, 0, 0); \
    __builtin_amdgcn_global_load_lds((const __attribute__((address_space(1))) void*)((GS) + row64K), \
        (__attribute__((address_space(3))) void*)((LS) + 4096), 16, 0, 0); \
} while (0)

// A-fragment reads: SET[mf][ks], byte off = CUR*32768 + (MH*64+mf*16)*128
#define LDA_TO(SET, CURLIT, MH) do { \
    DSR128O(SET[0][0], vA0, ((CURLIT)*32768+(((MH)*64+ 0)*128))); \
    DSR128O(SET[0][1], vA1, ((CURLIT)*32768+(((MH)*64+ 0)*128))); \
    DSR128O(SET[1][0], vA0, ((CURLIT)*32768+(((MH)*64+16)*128))); \
    DSR128O(SET[1][1], vA1, ((CURLIT)*32768+(((MH)*64+16)*128))); \
    DSR128O(SET[2][0], vA0, ((CURLIT)*32768+(((MH)*64+32)*128))); \
    DSR128O(SET[2][1], vA1, ((CURLIT)*32768+(((MH)*64+32)*128))); \
    DSR128O(SET[3][0], vA0, ((CURLIT)*32768+(((MH)*64+48)*128))); \
    DSR128O(SET[3][1], vA1, ((CURLIT)*32768+(((MH)*64+48)*128))); \
} while (0)

// B-fragment reads: SET[nf][ks], byte off = CUR*32768 + (NH*32+nf*16)*128
#define LDB_TO(SET, CURLIT, NH) do { \
    DSR128O(SET[0][0], vB0, ((CURLIT)*32768+(((NH)*32+ 0)*128))); \
    DSR128O(SET[0][1], vB1, ((CURLIT)*32768+(((NH)*32+ 0)*128))); \
    DSR128O(SET[1][0], vB0, ((CURLIT)*32768+(((NH)*32+16)*128))); \
    DSR128O(SET[1][1], vB1, ((CURLIT)*32768+(((NH)*32+16)*128))); \
} while (0)

#define QUADS(AS, BS, MH, NH) do { \
    _Pragma("unroll") for (int ks = 0; ks < 2; ++ks) \
    _Pragma("unroll") for (int mf = 0; mf < 4; ++mf) \
    _Pragma("unroll") for (int nf = 0; nf < 2; ++nf) \
        acc[(MH)*4+mf][(NH)*2+nf] = __builtin_amdgcn_mfma_f32_16x16x32_bf16( \
            AS[mf][ks], BS[nf][ks], acc[(MH)*4+mf][(NH)*2+nf], 0, 0, 0); \
} while (0)

#define TILE(CUR, NXT, S) do { \
    const u16* gA1 = Ag + (size_t)(((S)+1 < NT) ? (S)+1 : NT-1) * KTILE; \
    const u16* gA2 = Ag + (size_t)(((S)+2 < NT) ? (S)+2 : NT-1) * KTILE; \
    const u16* gB2 = Bg + (size_t)(((S)+2 < NT) ? (S)+2 : NT-1) * KTILE; \
    u16* lA1 = Al + (NXT) * 16384; \
    u16* lA2 = Al + (CUR) * 16384; \
    u16* lB2 = Bl + (CUR) * 16384; \
    /* ph1: q(0,0) */ \
    LDB_TO(bf_b, CUR, 1); \
    STAGE_SLOT(gA1 + halfGA, lA1 + 8192); \
    BAR(); \
    asm volatile("s_waitcnt lgkmcnt(4)" ::: "memory"); SFENCE(); \
    __builtin_amdgcn_s_setprio(1); QUADS(af_a, bf_a, 0, 0); __builtin_amdgcn_s_setprio(0); \
    BAR(); \
    /* ph2: q(0,1) */ \
    LDA_TO(af_b, CUR, 1); \
    BAR(); \
    asm volatile("s_waitcnt lgkmcnt(8)" ::: "memory"); SFENCE(); \
    __builtin_amdgcn_s_setprio(1); QUADS(af_a, bf_b, 0, 1); __builtin_amdgcn_s_setprio(0); \
    BAR(); \
    /* ph3: q(1,0) + vmcnt checkpoint before trailing barrier */ \
    STAGE_SLOT(gB2, lB2); \
    BAR(); \
    asm volatile("s_waitcnt lgkmcnt(0)" ::: "memory"); SFENCE(); \
    __builtin_amdgcn_s_setprio(1); QUADS(af_b, bf_a, 1, 0); __builtin_amdgcn_s_setprio(0); \
    SFENCE(); \
    asm volatile("s_waitcnt vmcnt(2)" ::: "memory"); \
    BAR(); \
    /* ph4: q(1,1) + prefetch next tile's q(0,0) frags */ \
    LDA_TO(af_a, NXT, 0); \
    LDB_TO(bf_a, NXT, 0); \
    STAGE_SLOT(gB2 + halfGA, lB2 + 8192); \
    STAGE_SLOT(gA2, lA2); \
    BAR(); \
    __builtin_amdgcn_s_setprio(1); QUADS(af_b, bf_b, 1, 1); __builtin_amdgcn_s_setprio(0); \
    BAR(); \
} while (0)

__global__ __launch_bounds__(512, 2) void gemm_k(
    const u16* __restrict__ A, const u16* __restrict__ B,
    const float* __restrict__ bias, const unsigned* __restrict__ scal,
    float* __restrict__ out, int M, int N, int K)
{
    __shared__ u16 As[2 * 256 * 64];   // 64 KB
    __shared__ u16 Bs[2 * 256 * 64];   // 64 KB

    const int tid = threadIdx.x;       // 0..511
    const int l   = tid & 63;
    const int wv  = tid >> 6;          // 0..7
    const int wm  = wv >> 2;           // 0..1  (M half)
    const int wn  = wv & 3;            // 0..3  (N quarter)

    // XCD-aware bijective block swizzle (m204)
    const int nTM = M / 256, nTN = N / 256;
    const int nwg = nTM * nTN;
    const int orig = blockIdx.x;
    const int xcd = orig & 7, lid = orig >> 3;
    const int q8 = nwg >> 3, r8 = nwg & 7;
    const int swz = (xcd < r8 ? xcd * (q8 + 1) : r8 * (q8 + 1) + (xcd - r8) * q8) + lid;
    const long tileM = (long)(swz % nTM) * 256;
    const long tileN = (long)(swz / nTM) * 256;

    // ---- staging addresses (per-lane global src, wave-uniform LDS dst) ----
    const int srow  = tid >> 3;              // 0..63 within half
    const int sslot = tid & 7;               // 16B chunk slot
    const int schunk = sslot ^ (srow & 7);   // inverse-swizzled source chunk
    const size_t row64K = (size_t)64 * K;
    const size_t halfGA = (size_t)128 * K;
    const u16* Ag = A + (size_t)(tileM + srow) * K + schunk * 8;
    const u16* Bg = B + (size_t)(tileN + srow) * K + schunk * 8;
    u16* Al = As + wv * 512;                 // wave-linear dest (base + lane*16B)
    u16* Bl = Bs + wv * 512;

    // ---- ds_read base addresses (16x16x32 frag: row = l&15, kchunk = l>>4) ----
    const int lr = l & 15;
    const int hi = l >> 4;
    const int ca0 = hi ^ (lr & 7);           // swizzled chunk, ks=0
    const int ca1 = ca0 ^ 4;                 // ks=1 toggles chunk bit2
    const unsigned vA0 = (unsigned)(unsigned long long)
        (const __attribute__((address_space(3))) void*)(const void*)(As + (wm * 128 + lr) * 64 + ca0 * 8);
    const unsigned vA1 = (unsigned)(unsigned long long)
        (const __attribute__((address_space(3))) void*)(const void*)(As + (wm * 128 + lr) * 64 + ca1 * 8);
    const unsigned vB0 = (unsigned)(unsigned long long)
        (const __attribute__((address_space(3))) void*)(const void*)(Bs + (wn * 64 + lr) * 64 + ca0 * 8);
    const unsigned vB1 = (unsigned)(unsigned long long)
        (const __attribute__((address_space(3))) void*)(const void*)(Bs + (wn * 64 + lr) * 64 + ca1 * 8);

    floatx4 acc[8][4] = {};
    bf16x8 af_a[4][2], af_b[4][2], bf_a[2][2], bf_b[2][2];

    const int NT = K / KTILE;                // even (K % 128 == 0)

    // ---- prologue: stage B0, A0, B1, A1h0; retire A0,B0; prefetch q(0,0) frags ----
    STAGE_SLOT(Bg, Bl);                      // B0h0
    STAGE_SLOT(Bg + halfGA, Bl + 8192);      // B0h1
    STAGE_SLOT(Ag, Al);                      // A0h0
    STAGE_SLOT(Ag + halfGA, Al + 8192);      // A0h1
    {
        const u16* gB1 = Bg + (size_t)((1 < NT) ? 1 : 0) * KTILE;
        STAGE_SLOT(gB1, Bl + 16384);                 // B1h0
        STAGE_SLOT(gB1 + halfGA, Bl + 16384 + 8192); // B1h1
        const u16* gA1p = Ag + (size_t)((1 < NT) ? 1 : 0) * KTILE;
        STAGE_SLOT(gA1p, Al + 16384);                // A1h0
    }
    SFENCE();
    asm volatile("s_waitcnt vmcnt(6)" ::: "memory");  // A0,B0 resident; B1,A1h0 in flight
    BAR();
    LDA_TO(af_a, 0, 0);
    LDB_TO(bf_a, 0, 0);

    for (int s = 0; s < NT; s += 2) {
        TILE(0, 1, s);
        TILE(1, 0, s + 1);
    }

    SFENCE();
    asm volatile("s_waitcnt vmcnt(0) lgkmcnt(0)" ::: "memory");
    SFENCE();

    // ---- epilogue ----
    float ax = __uint_as_float(scal[0]);
    float aw = __uint_as_float(scal[1]);
    float gsx = 2688.0f / ax, gsw = 2688.0f / aw;
    float alpha = 1.0f / (gsx * gsw);

    // C/D (m89): col = lane&15, row = (lane>>4)*4 + reg
    #pragma unroll
    for (int nq = 0; nq < 4; ++nq) {
        const long col = tileN + wn * 64 + nq * 16 + lr;
        const float bv = bias[col];
        #pragma unroll
        for (int mq = 0; mq < 8; ++mq) {
            const long r0 = tileM + wm * 128 + mq * 16 + hi * 4;
            #pragma unroll
            for (int reg = 0; reg < 4; ++reg)
                out[(size_t)(r0 + reg) * N + col] = acc[mq][nq][reg] * alpha + bv;
        }
    }
}

// ---------------- launch ----------------
extern "C" void kernel_launch(void* const* d_in, const int* in_sizes, int n_in,
                              void* d_out, int out_size, void* d_ws, size_t ws_size,
                              hipStream_t stream) {
    const float* x    = (const float*)d_in[0];
    const float* W    = (const float*)d_in[1];
    const float* bias = (const float*)d_in[2];
    float* out = (float*)d_out;

    const int N = in_sizes[2];
    const int K = in_sizes[1] / N;
    const int M = in_sizes[0] / K;

    unsigned* scal = (unsigned*)d_ws;
    u16* Aq = (u16*)((char*)d_ws + 256);
    u16* Bq = Aq + (size_t)M * K;

    hipMemsetAsync(scal, 0, 8, stream);

    const int GX = 2048, GW = 1024;
    hipLaunchKernelGGL(amax_both_k, dim3(GX + GW), dim3(256), 0, stream,
                       (const float4*)x, (long)M * K / 4,
                       (const float4*)W, (long)N * K / 4, scal, GX);

    long nx4 = (long)M * K / 4;
    long nw4 = (long)N * K / 4;
    hipLaunchKernelGGL(quant_both_k, dim3(4096), dim3(256), 0, stream,
                       (const float4*)x, (const float4*)W,
                       (uint2*)Aq, (uint2*)Bq, scal, nx4, nx4 + nw4);

    hipLaunchKernelGGL(gemm_k, dim3((M / 256) * (N / 256)), dim3(512), 0, stream,
                       Aq, Bq, bias, scal, out, M, N, K);
}

// Round 9
// 535.419 us; speedup vs baseline: 1.0051x; 1.0051x over previous
//
#include <hip/hip_runtime.h>
#include <stdint.h>

typedef unsigned short u16;
typedef __bf16 bf16x8 __attribute__((ext_vector_type(8)));
typedef float floatx4 __attribute__((ext_vector_type(4)));

// ---------------- fused global amax (x and W in one launch) ----------------
__global__ void amax_both_k(const float4* __restrict__ x, long nx4,
                            const float4* __restrict__ w, long nw4,
                            unsigned* slots, int gx) {
    const float4* src; long n4; int bid, nb; unsigned* slot;
    if ((int)blockIdx.x < gx) { src = x; n4 = nx4; bid = blockIdx.x; nb = gx; slot = slots; }
    else { src = w; n4 = nw4; bid = blockIdx.x - gx; nb = gridDim.x - gx; slot = slots + 1; }
    float m = 0.0f;
    long stride = (long)nb * blockDim.x;
    for (long i = (long)bid * blockDim.x + threadIdx.x; i < n4; i += stride) {
        float4 v = src[i];
        m = fmaxf(m, fmaxf(fmaxf(fabsf(v.x), fabsf(v.y)), fmaxf(fabsf(v.z), fabsf(v.w))));
    }
    #pragma unroll
    for (int off = 32; off > 0; off >>= 1)
        m = fmaxf(m, __shfl_down(m, off, 64));
    __shared__ float sm[4];
    int lane = threadIdx.x & 63, wv = threadIdx.x >> 6;
    if (lane == 0) sm[wv] = m;
    __syncthreads();
    if (threadIdx.x == 0) {
        m = fmaxf(fmaxf(sm[0], sm[1]), fmaxf(sm[2], sm[3]));
        atomicMax(slot, __float_as_uint(m));   // nonneg fp32: uint order == float order
    }
}

// ---------------- quantization helpers ----------------
// RNE float -> e4m3fn for v in [0, 448]
__device__ __forceinline__ float e4m3_rne(float v) {
    unsigned u = __float_as_uint(v);
    u += 0x7FFFFu + ((u >> 20) & 1u);            // RNE keep 3 mantissa bits
    float hi = __uint_as_float(u & 0xFFF00000u);
    float lo = rintf(v * 512.0f) * 0.001953125f; // subnormal, step 2^-9
    return (v < 0.015625f) ? lo : hi;
}

// RNE to fp4 e2m1 {0,±0.5,1,1.5,2,3,4,6}
__device__ __forceinline__ float fp4_rne(float x) {
    float a = fminf(fabsf(x), 6.0f);
    unsigned u = __float_as_uint(a);
    u += 0x1FFFFFu + ((u >> 22) & 1u);           // RNE keep 1 mantissa bit (a >= 1)
    float hi = __uint_as_float(u & 0xFFC00000u);
    float lo = rintf(a + a) * 0.5f;              // a < 1: fixed step 0.5
    float q = (a < 1.0f) ? lo : hi;
    return copysignf(q, x);
}

// pack two fp32 (exactly representable in bf16) into 2 bf16 bit patterns
__device__ __forceinline__ unsigned pack2(float d0, float d1) {
    return (__float_as_uint(d0) >> 16) | (__float_as_uint(d1) & 0xFFFF0000u);
}

// Coalesced quant (verified R7): one float4/lane; 16-elem nvfp4 block = aligned
// lane-quad; block amax via __shfl_xor width-4. Same fp32 op sequence as reference.
__global__ void quant_both_k(const float4* __restrict__ x4, const float4* __restrict__ w4,
                             uint2* __restrict__ Aq2, uint2* __restrict__ Bq2,
                             const unsigned* __restrict__ slots, long nx4, long ntot4) {
    float ag0 = __uint_as_float(slots[0]);
    float ag1 = __uint_as_float(slots[1]);
    float gs0 = 2688.0f / ag0, gs1 = 2688.0f / ag1;
    float t0 = gs0 / 6.0f,     t1 = gs1 / 6.0f;
    long stride = (long)gridDim.x * blockDim.x;
    for (long i = (long)blockIdx.x * blockDim.x + threadIdx.x; i < ntot4; i += stride) {
        bool isx = i < nx4;
        float4 v = isx ? x4[i] : w4[i - nx4];
        float gs = isx ? gs0 : gs1;
        float t  = isx ? t0  : t1;
        float am = fmaxf(fmaxf(fabsf(v.x), fabsf(v.y)), fmaxf(fabsf(v.z), fabsf(v.w)));
        am = fmaxf(am, __shfl_xor(am, 1, 4));
        am = fmaxf(am, __shfl_xor(am, 2, 4));
        float sf = e4m3_rne(am * t);
        float r = gs / (sf > 0.0f ? sf : 1.0f);
        uint2 o;
        o.x = pack2(fp4_rne(v.x * r) * sf, fp4_rne(v.y * r) * sf);
        o.y = pack2(fp4_rne(v.z * r) * sf, fp4_rne(v.w * r) * sf);
        if (isx) Aq2[i] = o; else Bq2[i - nx4] = o;
    }
}

// ---------------- GEMM: 256x256 tile, BK=64, 4-phase schedule ----------------
// R9 = R5 structure (258.5us best) + WITHIN-PHASE staged lgkm waits:
// reads issued in consumption order (ks=0 set first), lgkmcnt(N) starts the ks=0
// MFMA octet while ks=1 reads drain, lgkmcnt(0) gates the ks=1 octet.
// Buffer/stage/vmcnt ledger identical to R5 (re-verified):
//   ph1 stage A(s+1)h0, ph2 A(s+1)h1, ph3 B(s+2)h0, ph4 B(s+2)h1 + vmcnt(4).
#define KTILE 64

#define SFENCE() __builtin_amdgcn_sched_barrier(0)
#define BAR() do { asm volatile("" ::: "memory"); SFENCE(); \
    __builtin_amdgcn_s_barrier(); SFENCE(); asm volatile("" ::: "memory"); } while (0)
#define LGKM(N) do { asm volatile("s_waitcnt lgkmcnt(" #N ")" ::: "memory"); SFENCE(); } while (0)

// inline-asm ds_read_b128: opaque to SIInsertWaitcnts (no auto vmcnt(0) before it)
#define DSR128(D, P) asm volatile("ds_read_b128 %0, %1" : "=v"(D) \
    : "v"((unsigned)(unsigned long long)(const __attribute__((address_space(3))) void*)(const void*)(P)))

#define STAGE_SLOT(GS, LS) do { \
    __builtin_amdgcn_global_load_lds((const __attribute__((address_space(1))) void*)(GS), \
        (__attribute__((address_space(3))) void*)(LS), 16, 0, 0); \
    __builtin_amdgcn_global_load_lds((const __attribute__((address_space(1))) void*)((GS) + row64K), \
        (__attribute__((address_space(3))) void*)((LS) + 4096), 16, 0, 0); \
} while (0)

// A-fragment reads for one ks set (4 reads, consumption order mf=0..3)
#define LDA_KS(CUR, MH, KS) do { \
    const int ck_ = (KS) ? ca1 : ca0; \
    DSR128(af[0][KS], aB + (CUR) * 16384 + (((MH) * 64 +  0) * 64) + ck_ * 8); \
    DSR128(af[1][KS], aB + (CUR) * 16384 + (((MH) * 64 + 16) * 64) + ck_ * 8); \
    DSR128(af[2][KS], aB + (CUR) * 16384 + (((MH) * 64 + 32) * 64) + ck_ * 8); \
    DSR128(af[3][KS], aB + (CUR) * 16384 + (((MH) * 64 + 48) * 64) + ck_ * 8); \
} while (0)

// B-fragment reads for one ks set (2 reads)
#define LDB_KS(CUR, NH, KS) do { \
    const int ck_ = (KS) ? ca1 : ca0; \
    DSR128(bf[(NH)*2+0][KS], bB + (CUR) * 16384 + (((NH) * 32 +  0) * 64) + ck_ * 8); \
    DSR128(bf[(NH)*2+1][KS], bB + (CUR) * 16384 + (((NH) * 32 + 16) * 64) + ck_ * 8); \
} while (0)

// one ks octet of MFMAs for quadrant (MH,NH)
#define QUAD_KS(MH, NH, KS) do { \
    _Pragma("unroll") for (int mf = 0; mf < 4; ++mf) \
    _Pragma("unroll") for (int nf = 0; nf < 2; ++nf) \
        acc[(MH)*4+mf][(NH)*2+nf] = __builtin_amdgcn_mfma_f32_16x16x32_bf16( \
            af[mf][KS], bf[(NH)*2+nf][KS], acc[(MH)*4+mf][(NH)*2+nf], 0, 0, 0); \
} while (0)

#define TILE(CUR, S) do { \
    const u16* gA1 = Ag + (size_t)(((S)+1 < NT) ? (S)+1 : NT-1) * KTILE; \
    const u16* gB2 = Bg + (size_t)(((S)+2 < NT) ? (S)+2 : NT-1) * KTILE; \
    u16* lA1 = Al + ((CUR)^1) * 16384; \
    u16* lB2 = Bl + (CUR) * 16384; \
    /* ph1: q(0,0) — 12 reads: ks0 set (6) then ks1 set (6) */ \
    LDA_KS(CUR, 0, 0); LDB_KS(CUR, 0, 0); \
    LDA_KS(CUR, 0, 1); LDB_KS(CUR, 0, 1); \
    STAGE_SLOT(gA1, lA1); \
    BAR(); \
    __builtin_amdgcn_s_setprio(1); \
    LGKM(6); QUAD_KS(0, 0, 0); \
    LGKM(0); QUAD_KS(0, 0, 1); \
    __builtin_amdgcn_s_setprio(0); \
    BAR(); \
    /* ph2: q(0,1) — 4 reads: bf[2..3] ks0 then ks1 (af persists from ph1) */ \
    LDB_KS(CUR, 1, 0); LDB_KS(CUR, 1, 1); \
    STAGE_SLOT(gA1 + halfGA, lA1 + 8192); \
    BAR(); \
    __builtin_amdgcn_s_setprio(1); \
    LGKM(2); QUAD_KS(0, 1, 0); \
    LGKM(0); QUAD_KS(0, 1, 1); \
    __builtin_amdgcn_s_setprio(0); \
    BAR(); \
    /* ph3: q(1,0) — 8 reads: af ks0 then ks1 (bf[0..1] persists from ph1) */ \
    LDA_KS(CUR, 1, 0); LDA_KS(CUR, 1, 1); \
    STAGE_SLOT(gB2, lB2); \
    BAR(); \
    __builtin_amdgcn_s_setprio(1); \
    LGKM(4); QUAD_KS(1, 0, 0); \
    LGKM(0); QUAD_KS(1, 0, 1); \
    __builtin_amdgcn_s_setprio(0); \
    BAR(); \
    /* ph4: q(1,1) — 0 reads; per-tile counted-vmcnt checkpoint */ \
    STAGE_SLOT(gB2 + halfGA, lB2 + 8192); \
    BAR(); \
    __builtin_amdgcn_s_setprio(1); QUAD_KS(1, 1, 0); QUAD_KS(1, 1, 1); __builtin_amdgcn_s_setprio(0); \
    SFENCE(); \
    asm volatile("s_waitcnt vmcnt(4)" ::: "memory"); \
    BAR(); \
} while (0)

__global__ __launch_bounds__(512, 2) void gemm_k(
    const u16* __restrict__ A, const u16* __restrict__ B,
    const float* __restrict__ bias, const unsigned* __restrict__ scal,
    float* __restrict__ out, int M, int N, int K)
{
    __shared__ u16 As[2 * 256 * 64];   // 64 KB
    __shared__ u16 Bs[2 * 256 * 64];   // 64 KB

    const int tid = threadIdx.x;       // 0..511
    const int l   = tid & 63;
    const int wv  = tid >> 6;          // 0..7
    const int wm  = wv >> 2;           // 0..1  (M half)
    const int wn  = wv & 3;            // 0..3  (N quarter)

    // XCD-aware bijective block swizzle (m204)
    const int nTM = M / 256, nTN = N / 256;
    const int nwg = nTM * nTN;
    const int orig = blockIdx.x;
    const int xcd = orig & 7, lid = orig >> 3;
    const int q8 = nwg >> 3, r8 = nwg & 7;
    const int swz = (xcd < r8 ? xcd * (q8 + 1) : r8 * (q8 + 1) + (xcd - r8) * q8) + lid;
    const long tileM = (long)(swz % nTM) * 256;
    const long tileN = (long)(swz / nTM) * 256;

    // ---- staging addresses (per-lane global src, wave-uniform LDS dst) ----
    const int srow  = tid >> 3;              // 0..63 within half
    const int sslot = tid & 7;               // 16B chunk slot
    const int schunk = sslot ^ (srow & 7);   // inverse-swizzled source chunk
    const size_t row64K = (size_t)64 * K;
    const size_t halfGA = (size_t)128 * K;
    const u16* Ag = A + (size_t)(tileM + srow) * K + schunk * 8;
    const u16* Bg = B + (size_t)(tileN + srow) * K + schunk * 8;
    u16* Al = As + wv * 512;                 // wave-linear dest (base + lane*16B)
    u16* Bl = Bs + wv * 512;

    // ---- ds_read addresses (16x16x32 frag: row = l&15, kchunk = l>>4) ----
    const int lr = l & 15;
    const int hi = l >> 4;
    const int ca0 = hi ^ (lr & 7);           // swizzled chunk, ks=0
    const int ca1 = ca0 ^ 4;                 // ks=1 toggles chunk bit2
    const u16* aB = As + (wm * 128 + lr) * 64;
    const u16* bB = Bs + (wn * 64 + lr) * 64;

    floatx4 acc[8][4] = {};
    bf16x8 af[4][2], bf[4][2];

    const int NT = K / KTILE;                // even (K % 128 == 0)

    // ---- prologue: B(0), A(0), B(1); leave B(1) (last 4 slots) in flight ----
    STAGE_SLOT(Bg, Bl);
    STAGE_SLOT(Bg + halfGA, Bl + 8192);
    STAGE_SLOT(Ag, Al);
    STAGE_SLOT(Ag + halfGA, Al + 8192);
    {
        const u16* gB1 = Bg + ((1 < NT) ? KTILE : 0);
        STAGE_SLOT(gB1, Bl + 16384);
        STAGE_SLOT(gB1 + halfGA, Bl + 16384 + 8192);
    }
    SFENCE();
    asm volatile("s_waitcnt vmcnt(4)" ::: "memory");
    BAR();

    for (int s = 0; s < NT; s += 2) {
        TILE(0, s);
        TILE(1, s + 1);
    }

    SFENCE();
    asm volatile("s_waitcnt vmcnt(0) lgkmcnt(0)" ::: "memory");
    SFENCE();

    // ---- epilogue ----
    float ax = __uint_as_float(scal[0]);
    float aw = __uint_as_float(scal[1]);
    float gsx = 2688.0f / ax, gsw = 2688.0f / aw;
    float alpha = 1.0f / (gsx * gsw);

    // C/D (m89): col = lane&15, row = (lane>>4)*4 + reg
    #pragma unroll
    for (int nq = 0; nq < 4; ++nq) {
        const long col = tileN + wn * 64 + nq * 16 + lr;
        const float bv = bias[col];
        #pragma unroll
        for (int mq = 0; mq < 8; ++mq) {
            const long r0 = tileM + wm * 128 + mq * 16 + hi * 4;
            #pragma unroll
            for (int reg = 0; reg < 4; ++reg)
                out[(size_t)(r0 + reg) * N + col] = acc[mq][nq][reg] * alpha + bv;
        }
    }
}

// ---------------- launch ----------------
extern "C" void kernel_launch(void* const* d_in, const int* in_sizes, int n_in,
                              void* d_out, int out_size, void* d_ws, size_t ws_size,
                              hipStream_t stream) {
    const float* x    = (const float*)d_in[0];
    const float* W    = (const float*)d_in[1];
    const float* bias = (const float*)d_in[2];
    float* out = (float*)d_out;

    const int N = in_sizes[2];
    const int K = in_sizes[1] / N;
    const int M = in_sizes[0] / K;

    unsigned* scal = (unsigned*)d_ws;
    u16* Aq = (u16*)((char*)d_ws + 256);
    u16* Bq = Aq + (size_t)M * K;

    hipMemsetAsync(scal, 0, 8, stream);

    const int GX = 2048, GW = 1024;
    hipLaunchKernelGGL(amax_both_k, dim3(GX + GW), dim3(256), 0, stream,
                       (const float4*)x, (long)M * K / 4,
                       (const float4*)W, (long)N * K / 4, scal, GX);

    long nx4 = (long)M * K / 4;
    long nw4 = (long)N * K / 4;
    hipLaunchKernelGGL(quant_both_k, dim3(4096), dim3(256), 0, stream,
                       (const float4*)x, (const float4*)W,
                       (uint2*)Aq, (uint2*)Bq, scal, nx4, nx4 + nw4);

    hipLaunchKernelGGL(gemm_k, dim3((M / 256) * (N / 256)), dim3(512), 0, stream,
                       Aq, Bq, bias, scal, out, M, N, K);
}